// Round 1
// baseline (227.094 us; speedup 1.0000x reference)
//
#include <hip/hip_runtime.h>
#include <hip/hip_cooperative_groups.h>

namespace cg = cooperative_groups;

#define DIM 512
#define BK 32
#define ASTRIDE 40   // ushorts per A-row: 32 payload + 8 pad (80B) -> conflict-free frag reads

typedef unsigned int uint;
typedef unsigned short ushort;
typedef __attribute__((ext_vector_type(8))) short short8;
typedef __attribute__((ext_vector_type(4))) float f32x4;

#define GLOAD_LDS(g, l) __builtin_amdgcn_global_load_lds( \
    (const __attribute__((address_space(1))) void*)(g), \
    (__attribute__((address_space(3))) void*)(l), 16, 0, 0)

// Pack two fp32 -> two bf16 (round-to-nearest-ish via +0x8000, then byte-perm pack).
__device__ __forceinline__ uint pack_bf16(float a, float b) {
    union { float f; uint u; } ua, ub;
    ua.f = a; ub.f = b;
    uint x0 = ua.u + 0x8000u;
    uint x1 = ub.u + 0x8000u;
    return __builtin_amdgcn_perm(x1, x0, 0x07060302);
}

// =====================================================================
// Legacy 3-kernel path (kept as fallback if cooperative launch fails)
// =====================================================================
__global__ void zconv_kernel(const float* __restrict__ z, ushort* __restrict__ zb) {
    int t = blockIdx.x * 256 + threadIdx.x;
    int f = t * 8;
    float4 a = *(const float4*)(z + f);
    float4 b = *(const float4*)(z + f + 4);
    uint4 o;
    o.x = pack_bf16(a.x, a.y);
    o.y = pack_bf16(a.z, a.w);
    o.z = pack_bf16(b.x, b.y);
    o.w = pack_bf16(b.z, b.w);
    *(uint4*)(zb + f) = o;
}

__global__ void __launch_bounds__(512, 4)
gemm_fused(const float* __restrict__ x, const float* __restrict__ y,
           const ushort* __restrict__ zb, const float* __restrict__ z,
           float* __restrict__ rowM, float* __restrict__ rowS,
           float* __restrict__ colM, float* __restrict__ colS,
           float* __restrict__ diag, uint* __restrict__ counter) {
    __shared__ __align__(16) float xs[DIM];
    __shared__ __align__(16) ushort As[2][128 * ASTRIDE];
    __shared__ __align__(16) ushort Bs[2][256 * BK];
    __shared__ float redA[128 * 4];
    __shared__ float rowMaxS[128];
    __shared__ float redB[256 * 2];
    __shared__ float colMaxS[256];
    __shared__ float dred[8];

    const int tid = threadIdx.x;
    const int a   = blockIdx.x >> 1;
    const int rt  = blockIdx.x & 1;

    if (blockIdx.x == 0 && tid == 0) *counter = 0u;

    xs[tid] = x[a * DIM + tid];

    const int lane = tid & 63;
    const int wave = tid >> 6;
    const int quad = lane >> 4;
    const int ln15 = lane & 15;
    const int wr = wave >> 2;
    const int wc = wave & 3;

    if (rt == 0) {
        float p = xs[tid] * y[a * DIM + tid] * z[a * DIM + tid];
        #pragma unroll
        for (int m = 1; m < 64; m <<= 1) p += __shfl_xor(p, m, 64);
        if (lane == 0) dred[wave] = p;
        __syncthreads();
        if (tid == 0) {
            float s = 0.f;
            #pragma unroll
            for (int w2 = 0; w2 < 8; ++w2) s += dred[w2];
            diag[a] = s;
        }
    }
    __syncthreads();

    f32x4 acc[4][4];
    #pragma unroll
    for (int i = 0; i < 4; ++i)
        #pragma unroll
        for (int j = 0; j < 4; ++j)
            acc[i][j] = (f32x4){0.f, 0.f, 0.f, 0.f};

    const int rA = tid >> 2;
    const int kA = (tid & 3) * 8;
    const float* yrow = y + (rt * 128 + rA) * DIM + kA;

    const int s0 = wave * 128 + lane;
    const int row0 = s0 >> 2, kc0 = ((s0 & 3) - (row0 >> 1)) & 3;
    const ushort* gB0 = zb + row0 * DIM + kc0 * 8;
    const int s1 = s0 + 64;
    const int row1 = s1 >> 2, kc1 = ((s1 & 3) - (row1 >> 1)) & 3;
    const ushort* gB1 = zb + row1 * DIM + kc1 * 8;

    GLOAD_LDS(gB0, &Bs[0][wave * 1024]);
    GLOAD_LDS(gB1, &Bs[0][wave * 1024 + 512]);
    float4 ya = *(const float4*)(yrow);
    float4 yb = *(const float4*)(yrow + 4);
    {
        float4 x0 = *(const float4*)(xs + kA);
        float4 x1 = *(const float4*)(xs + kA + 4);
        uint4 o;
        o.x = pack_bf16(ya.x * x0.x, ya.y * x0.y);
        o.y = pack_bf16(ya.z * x0.z, ya.w * x0.w);
        o.z = pack_bf16(yb.x * x1.x, yb.y * x1.y);
        o.w = pack_bf16(yb.z * x1.z, yb.w * x1.w);
        *(uint4*)(&As[0][rA * ASTRIDE + kA]) = o;
    }
    ya = *(const float4*)(yrow + 32);
    yb = *(const float4*)(yrow + 36);

    #pragma unroll 2
    for (int kt = 0; kt < 16; ++kt) {
        const int cur = kt & 1, nxt = cur ^ 1;
        __syncthreads();
        if (kt < 15) {
            GLOAD_LDS(gB0 + (kt + 1) * 32, &Bs[nxt][wave * 1024]);
            GLOAD_LDS(gB1 + (kt + 1) * 32, &Bs[nxt][wave * 1024 + 512]);
        }
        short8 af[4], bfr[4];
        #pragma unroll
        for (int i = 0; i < 4; ++i)
            af[i] = *(const short8*)(&As[cur][(wr * 64 + i * 16 + ln15) * ASTRIDE + quad * 8]);
        #pragma unroll
        for (int j = 0; j < 4; ++j) {
            int row = wc * 64 + j * 16 + ln15;
            int pos = row * 4 + ((quad + (row >> 1)) & 3);
            bfr[j] = *(const short8*)(&Bs[cur][pos * 8]);
        }
        #pragma unroll
        for (int i = 0; i < 4; ++i)
            #pragma unroll
            for (int j = 0; j < 4; ++j)
                acc[i][j] = __builtin_amdgcn_mfma_f32_16x16x32_bf16(af[i], bfr[j], acc[i][j], 0, 0, 0);
        if (kt < 15) {
            const int k1 = (kt + 1) * 32;
            float4 x0 = *(const float4*)(xs + k1 + kA);
            float4 x1 = *(const float4*)(xs + k1 + kA + 4);
            uint4 o;
            o.x = pack_bf16(ya.x * x0.x, ya.y * x0.y);
            o.y = pack_bf16(ya.z * x0.z, ya.w * x0.w);
            o.z = pack_bf16(yb.x * x1.x, yb.y * x1.y);
            o.w = pack_bf16(yb.z * x1.z, yb.w * x1.w);
            *(uint4*)(&As[nxt][rA * ASTRIDE + kA]) = o;
            if (kt < 14) {
                ya = *(const float4*)(yrow + (kt + 2) * 32);
                yb = *(const float4*)(yrow + (kt + 2) * 32 + 4);
            }
        }
    }
    __syncthreads();

    #pragma unroll
    for (int i = 0; i < 4; ++i) {
        #pragma unroll
        for (int reg = 0; reg < 4; ++reg) {
            float m = fmaxf(fmaxf(acc[i][0][reg], acc[i][1][reg]),
                            fmaxf(acc[i][2][reg], acc[i][3][reg]));
            #pragma unroll
            for (int d = 1; d < 16; d <<= 1) m = fmaxf(m, __shfl_xor(m, d, 64));
            if (ln15 == 0) redA[(wr * 64 + i * 16 + quad * 4 + reg) * 4 + wc] = m;
        }
    }
    __syncthreads();
    if (tid < 128) {
        float m = fmaxf(fmaxf(redA[tid * 4 + 0], redA[tid * 4 + 1]),
                        fmaxf(redA[tid * 4 + 2], redA[tid * 4 + 3]));
        rowMaxS[tid] = m;
    }
    __syncthreads();
    #pragma unroll
    for (int i = 0; i < 4; ++i) {
        #pragma unroll
        for (int reg = 0; reg < 4; ++reg) {
            int r = wr * 64 + i * 16 + quad * 4 + reg;
            float rm = rowMaxS[r];
            float s = __expf(acc[i][0][reg] - rm) + __expf(acc[i][1][reg] - rm)
                    + __expf(acc[i][2][reg] - rm) + __expf(acc[i][3][reg] - rm);
            #pragma unroll
            for (int d = 1; d < 16; d <<= 1) s += __shfl_xor(s, d, 64);
            if (ln15 == 0) redA[r * 4 + wc] = s;
        }
    }
    __syncthreads();
    if (tid < 128) {
        float s = redA[tid * 4 + 0] + redA[tid * 4 + 1] + redA[tid * 4 + 2] + redA[tid * 4 + 3];
        int rg = rt * 128 + tid;
        rowM[a * 256 + rg] = rowMaxS[tid];
        rowS[a * 256 + rg] = s;
    }

    #pragma unroll
    for (int j = 0; j < 4; ++j) {
        float m = -3.4e38f;
        #pragma unroll
        for (int i = 0; i < 4; ++i)
            #pragma unroll
            for (int reg = 0; reg < 4; ++reg)
                m = fmaxf(m, acc[i][j][reg]);
        m = fmaxf(m, __shfl_xor(m, 16, 64));
        m = fmaxf(m, __shfl_xor(m, 32, 64));
        if (quad == 0) redB[(wc * 64 + j * 16 + ln15) * 2 + wr] = m;
    }
    __syncthreads();
    if (tid < 256) colMaxS[tid] = fmaxf(redB[tid * 2], redB[tid * 2 + 1]);
    __syncthreads();
    #pragma unroll
    for (int j = 0; j < 4; ++j) {
        int n = wc * 64 + j * 16 + ln15;
        float cm = colMaxS[n];
        float s = 0.f;
        #pragma unroll
        for (int i = 0; i < 4; ++i)
            #pragma unroll
            for (int reg = 0; reg < 4; ++reg)
                s += __expf(acc[i][j][reg] - cm);
        s += __shfl_xor(s, 16, 64);
        s += __shfl_xor(s, 32, 64);
        if (quad == 0) redB[n * 2 + wr] = s;
    }
    __syncthreads();
    if (tid < 256) {
        float s = redB[tid * 2] + redB[tid * 2 + 1];
        colM[(a * 256 + tid) * 2 + rt] = colMaxS[tid];
        colS[(a * 256 + tid) * 2 + rt] = s;
    }
}

__device__ __forceinline__ float blk_max(float v, float* sm) {
    #pragma unroll
    for (int d = 1; d < 64; d <<= 1) v = fmaxf(v, __shfl_xor(v, d, 64));
    __syncthreads();
    if ((threadIdx.x & 63) == 0) sm[threadIdx.x >> 6] = v;
    __syncthreads();
    return fmaxf(fmaxf(sm[0], sm[1]), fmaxf(sm[2], sm[3]));
}
__device__ __forceinline__ float blk_sum(float v, float* sm) {
    #pragma unroll
    for (int d = 1; d < 64; d <<= 1) v += __shfl_xor(v, d, 64);
    __syncthreads();
    if ((threadIdx.x & 63) == 0) sm[threadIdx.x >> 6] = v;
    __syncthreads();
    return sm[0] + sm[1] + sm[2] + sm[3];
}

__global__ void combine_final(const float* __restrict__ rowM, const float* __restrict__ rowS,
                              const float* __restrict__ colM, const float* __restrict__ colS,
                              const float* __restrict__ diag,
                              float* __restrict__ m123, uint* __restrict__ counter,
                              float* __restrict__ out) {
    __shared__ float sm[4];
    __shared__ uint isLast;
    int b = blockIdx.x, t = threadIdx.x;
    float m = rowM[b * 256 + t], s = rowS[b * 256 + t];
    float M = blk_max(m, sm);
    float S = blk_sum(s * __expf(m - M), sm);
    float M1 = M + __logf(S);
    m = rowM[t * 256 + b]; s = rowS[t * 256 + b];
    M = blk_max(m, sm);
    S = blk_sum(s * __expf(m - M), sm);
    float M2 = M + __logf(S);
    float am = colM[(t * 256 + b) * 2 + 0], av = colS[(t * 256 + b) * 2 + 0];
    float bm = colM[(t * 256 + b) * 2 + 1], bv = colS[(t * 256 + b) * 2 + 1];
    m = fmaxf(am, bm);
    s = av * __expf(am - m) + bv * __expf(bm - m);
    M = blk_max(m, sm);
    S = blk_sum(s * __expf(m - M), sm);
    float M3 = M + __logf(S);
    if (t == 0) {
        m123[b] = M1 + M2 + M3;
        __threadfence();
        isLast = (atomicAdd(counter, 1u) == 255u) ? 1u : 0u;
    }
    __syncthreads();
    if (isLast) {
        __threadfence();
        const volatile float* vm = (const volatile float*)m123;
        const volatile float* vd = (const volatile float*)diag;
        float S1 = blk_sum(vm[t], sm);
        float S2 = blk_sum(vd[t], sm);
        if (t == 0) out[0] = S1 / 768.0f - S2 / 256.0f;
    }
}

// =====================================================================
// Fused single-launch cooperative kernel:
//   phase 0: z->bf16 (blocks 0..127) + exact diag (rt==0)   [grid.sync]
//   phase 1: batched GEMM + LSE partials (identical hot loop) [grid.sync]
//   phase 2: per-index LSE combine (rt==0 blocks) + last-block final
// 512 blocks x 512 threads = 2 blocks/CU (LDS 59.5KB, VGPR<=128) -> the
// cooperative occupancy check passes and grid.sync is legal.
// =====================================================================

// 512-thread-block variants: only tid<256 carry data, all threads barrier.
__device__ __forceinline__ float blk_max512(float v, float* sm) {
    #pragma unroll
    for (int d = 1; d < 64; d <<= 1) v = fmaxf(v, __shfl_xor(v, d, 64));
    __syncthreads();
    if (threadIdx.x < 256 && (threadIdx.x & 63) == 0) sm[threadIdx.x >> 6] = v;
    __syncthreads();
    return fmaxf(fmaxf(sm[0], sm[1]), fmaxf(sm[2], sm[3]));
}
__device__ __forceinline__ float blk_sum512(float v, float* sm) {
    #pragma unroll
    for (int d = 1; d < 64; d <<= 1) v += __shfl_xor(v, d, 64);
    __syncthreads();
    if (threadIdx.x < 256 && (threadIdx.x & 63) == 0) sm[threadIdx.x >> 6] = v;
    __syncthreads();
    return sm[0] + sm[1] + sm[2] + sm[3];
}

__global__ void __launch_bounds__(512, 4)
fused_all(const float* __restrict__ x, const float* __restrict__ y,
          const float* __restrict__ z, ushort* __restrict__ zb,
          float* __restrict__ rowM, float* __restrict__ rowS,
          float* __restrict__ colM, float* __restrict__ colS,
          float* __restrict__ diag, float* __restrict__ m123,
          uint* __restrict__ counter, float* __restrict__ out) {
    __shared__ __align__(16) float xs[DIM];
    __shared__ __align__(16) ushort As[2][128 * ASTRIDE];
    __shared__ __align__(16) ushort Bs[2][256 * BK];
    __shared__ float redA[128 * 4];
    __shared__ float rowMaxS[128];
    __shared__ float redB[256 * 2];
    __shared__ float colMaxS[256];
    __shared__ float dred[8];
    __shared__ uint isLastS;

    const int tid = threadIdx.x;
    const int a   = blockIdx.x >> 1;
    const int rt  = blockIdx.x & 1;

    // ---- phase 0: z -> bf16 (one uint per thread over blocks 0..127) ----
    if (blockIdx.x < 128) {
        int idx = blockIdx.x * 512 + tid;      // 65536 uints = 131072 bf16
        float2 v = *(const float2*)(z + idx * 2);
        ((uint*)zb)[idx] = pack_bf16(v.x, v.y);
    }
    if (blockIdx.x == 0 && tid == 0) *counter = 0u;

    xs[tid] = x[a * DIM + tid];

    const int lane = tid & 63;
    const int wave = tid >> 6;
    const int quad = lane >> 4;
    const int ln15 = lane & 15;
    const int wr = wave >> 2;
    const int wc = wave & 3;

    // ---- fused diag: T[a,a,a] exact fp32 (rt==0 blocks only) ----
    if (rt == 0) {
        float p = xs[tid] * y[a * DIM + tid] * z[a * DIM + tid];
        #pragma unroll
        for (int m = 1; m < 64; m <<= 1) p += __shfl_xor(p, m, 64);
        if (lane == 0) dred[wave] = p;
        __syncthreads();
        if (tid == 0) {
            float s = 0.f;
            #pragma unroll
            for (int w2 = 0; w2 < 8; ++w2) s += dred[w2];
            diag[a] = s;
        }
    }
    __syncthreads();   // xs visible to all

    cg::this_grid().sync();   // zb fully written + counter reset visible

    // ---- phase 1: GEMM + LSE partials (identical to proven kernel) ----
    f32x4 acc[4][4];
    #pragma unroll
    for (int i = 0; i < 4; ++i)
        #pragma unroll
        for (int j = 0; j < 4; ++j)
            acc[i][j] = (f32x4){0.f, 0.f, 0.f, 0.f};

    const int rA = tid >> 2;
    const int kA = (tid & 3) * 8;
    const float* yrow = y + (rt * 128 + rA) * DIM + kA;

    const int s0 = wave * 128 + lane;
    const int row0 = s0 >> 2, kc0 = ((s0 & 3) - (row0 >> 1)) & 3;
    const ushort* gB0 = zb + row0 * DIM + kc0 * 8;
    const int s1 = s0 + 64;
    const int row1 = s1 >> 2, kc1 = ((s1 & 3) - (row1 >> 1)) & 3;
    const ushort* gB1 = zb + row1 * DIM + kc1 * 8;

    GLOAD_LDS(gB0, &Bs[0][wave * 1024]);
    GLOAD_LDS(gB1, &Bs[0][wave * 1024 + 512]);
    float4 ya = *(const float4*)(yrow);
    float4 yb = *(const float4*)(yrow + 4);
    {
        float4 x0 = *(const float4*)(xs + kA);
        float4 x1 = *(const float4*)(xs + kA + 4);
        uint4 o;
        o.x = pack_bf16(ya.x * x0.x, ya.y * x0.y);
        o.y = pack_bf16(ya.z * x0.z, ya.w * x0.w);
        o.z = pack_bf16(yb.x * x1.x, yb.y * x1.y);
        o.w = pack_bf16(yb.z * x1.z, yb.w * x1.w);
        *(uint4*)(&As[0][rA * ASTRIDE + kA]) = o;
    }
    ya = *(const float4*)(yrow + 32);
    yb = *(const float4*)(yrow + 36);

    #pragma unroll 2
    for (int kt = 0; kt < 16; ++kt) {
        const int cur = kt & 1, nxt = cur ^ 1;
        __syncthreads();
        if (kt < 15) {
            GLOAD_LDS(gB0 + (kt + 1) * 32, &Bs[nxt][wave * 1024]);
            GLOAD_LDS(gB1 + (kt + 1) * 32, &Bs[nxt][wave * 1024 + 512]);
        }
        short8 af[4], bfr[4];
        #pragma unroll
        for (int i = 0; i < 4; ++i)
            af[i] = *(const short8*)(&As[cur][(wr * 64 + i * 16 + ln15) * ASTRIDE + quad * 8]);
        #pragma unroll
        for (int j = 0; j < 4; ++j) {
            int row = wc * 64 + j * 16 + ln15;
            int pos = row * 4 + ((quad + (row >> 1)) & 3);
            bfr[j] = *(const short8*)(&Bs[cur][pos * 8]);
        }
        #pragma unroll
        for (int i = 0; i < 4; ++i)
            #pragma unroll
            for (int j = 0; j < 4; ++j)
                acc[i][j] = __builtin_amdgcn_mfma_f32_16x16x32_bf16(af[i], bfr[j], acc[i][j], 0, 0, 0);
        if (kt < 15) {
            const int k1 = (kt + 1) * 32;
            float4 x0 = *(const float4*)(xs + k1 + kA);
            float4 x1 = *(const float4*)(xs + k1 + kA + 4);
            uint4 o;
            o.x = pack_bf16(ya.x * x0.x, ya.y * x0.y);
            o.y = pack_bf16(ya.z * x0.z, ya.w * x0.w);
            o.z = pack_bf16(yb.x * x1.x, yb.y * x1.y);
            o.w = pack_bf16(yb.z * x1.z, yb.w * x1.w);
            *(uint4*)(&As[nxt][rA * ASTRIDE + kA]) = o;
            if (kt < 14) {
                ya = *(const float4*)(yrow + (kt + 2) * 32);
                yb = *(const float4*)(yrow + (kt + 2) * 32 + 4);
            }
        }
    }
    __syncthreads();

    // ===== row-wise LSE partials =====
    #pragma unroll
    for (int i = 0; i < 4; ++i) {
        #pragma unroll
        for (int reg = 0; reg < 4; ++reg) {
            float m = fmaxf(fmaxf(acc[i][0][reg], acc[i][1][reg]),
                            fmaxf(acc[i][2][reg], acc[i][3][reg]));
            #pragma unroll
            for (int d = 1; d < 16; d <<= 1) m = fmaxf(m, __shfl_xor(m, d, 64));
            if (ln15 == 0) redA[(wr * 64 + i * 16 + quad * 4 + reg) * 4 + wc] = m;
        }
    }
    __syncthreads();
    if (tid < 128) {
        float m = fmaxf(fmaxf(redA[tid * 4 + 0], redA[tid * 4 + 1]),
                        fmaxf(redA[tid * 4 + 2], redA[tid * 4 + 3]));
        rowMaxS[tid] = m;
    }
    __syncthreads();
    #pragma unroll
    for (int i = 0; i < 4; ++i) {
        #pragma unroll
        for (int reg = 0; reg < 4; ++reg) {
            int r = wr * 64 + i * 16 + quad * 4 + reg;
            float rm = rowMaxS[r];
            float s = __expf(acc[i][0][reg] - rm) + __expf(acc[i][1][reg] - rm)
                    + __expf(acc[i][2][reg] - rm) + __expf(acc[i][3][reg] - rm);
            #pragma unroll
            for (int d = 1; d < 16; d <<= 1) s += __shfl_xor(s, d, 64);
            if (ln15 == 0) redA[r * 4 + wc] = s;
        }
    }
    __syncthreads();
    if (tid < 128) {
        float s = redA[tid * 4 + 0] + redA[tid * 4 + 1] + redA[tid * 4 + 2] + redA[tid * 4 + 3];
        int rg = rt * 128 + tid;
        rowM[a * 256 + rg] = rowMaxS[tid];
        rowS[a * 256 + rg] = s;
    }

    // ===== col-wise LSE partials =====
    #pragma unroll
    for (int j = 0; j < 4; ++j) {
        float m = -3.4e38f;
        #pragma unroll
        for (int i = 0; i < 4; ++i)
            #pragma unroll
            for (int reg = 0; reg < 4; ++reg)
                m = fmaxf(m, acc[i][j][reg]);
        m = fmaxf(m, __shfl_xor(m, 16, 64));
        m = fmaxf(m, __shfl_xor(m, 32, 64));
        if (quad == 0) redB[(wc * 64 + j * 16 + ln15) * 2 + wr] = m;
    }
    __syncthreads();
    if (tid < 256) colMaxS[tid] = fmaxf(redB[tid * 2], redB[tid * 2 + 1]);
    __syncthreads();
    #pragma unroll
    for (int j = 0; j < 4; ++j) {
        int n = wc * 64 + j * 16 + ln15;
        float cm = colMaxS[n];
        float s = 0.f;
        #pragma unroll
        for (int i = 0; i < 4; ++i)
            #pragma unroll
            for (int reg = 0; reg < 4; ++reg)
                s += __expf(acc[i][j][reg] - cm);
        s += __shfl_xor(s, 16, 64);
        s += __shfl_xor(s, 32, 64);
        if (quad == 0) redB[n * 2 + wr] = s;
    }
    __syncthreads();
    if (tid < 256) {
        float s = redB[tid * 2] + redB[tid * 2 + 1];
        colM[(a * 256 + tid) * 2 + rt] = colMaxS[tid];
        colS[(a * 256 + tid) * 2 + rt] = s;
    }

    cg::this_grid().sync();   // all partials visible device-wide

    // ---- phase 2: combine (rt==0 blocks handle b=a; tid<256 active) ----
    if (rt == 0) {
        const int b = a;
        const int t = tid;
        const bool act = t < 256;
        float m = act ? rowM[b * 256 + t] : -3.4e38f;
        float s = act ? rowS[b * 256 + t] : 0.f;
        float M = blk_max512(m, dred);
        float S = blk_sum512(act ? s * __expf(m - M) : 0.f, dred);
        float M1 = M + __logf(S);
        m = act ? rowM[t * 256 + b] : -3.4e38f;
        s = act ? rowS[t * 256 + b] : 0.f;
        M = blk_max512(m, dred);
        S = blk_sum512(act ? s * __expf(m - M) : 0.f, dred);
        float M2 = M + __logf(S);
        float am = act ? colM[(t * 256 + b) * 2 + 0] : -3.4e38f;
        float av = act ? colS[(t * 256 + b) * 2 + 0] : 0.f;
        float bm = act ? colM[(t * 256 + b) * 2 + 1] : -3.4e38f;
        float bv = act ? colS[(t * 256 + b) * 2 + 1] : 0.f;
        m = fmaxf(am, bm);
        s = av * __expf(am - m) + bv * __expf(bm - m);
        M = blk_max512(m, dred);
        S = blk_sum512(act ? s * __expf(m - M) : 0.f, dred);
        float M3 = M + __logf(S);
        if (t == 0) {
            m123[b] = M1 + M2 + M3;
            __threadfence();
            isLastS = (atomicAdd(counter, 1u) == 255u) ? 1u : 0u;
        }
        __syncthreads();
        if (isLastS) {
            __threadfence();
            const volatile float* vm = (const volatile float*)m123;
            const volatile float* vd = (const volatile float*)diag;
            float S1 = blk_sum512(act ? vm[t] : 0.f, dred);
            float S2 = blk_sum512(act ? vd[t] : 0.f, dred);
            if (t == 0) out[0] = S1 / 768.0f - S2 / 256.0f;
        }
    }
}

extern "C" void kernel_launch(void* const* d_in, const int* in_sizes, int n_in,
                              void* d_out, int out_size, void* d_ws, size_t ws_size,
                              hipStream_t stream) {
    const float* x = (const float*)d_in[0];
    const float* y = (const float*)d_in[1];
    const float* z = (const float*)d_in[2];
    char* w = (char*)d_ws;
    ushort* zb  = (ushort*)(w);                  // 262144 B
    float* rowM = (float*)(w + 262144);          // 262144 B
    float* rowS = (float*)(w + 524288);          // 262144 B
    float* colM = (float*)(w + 786432);          // 524288 B
    float* colS = (float*)(w + 1310720);         // 524288 B
    float* diag = (float*)(w + 1835008);         // 1024 B
    float* m123 = (float*)(w + 1836032);         // 1024 B
    uint*  counter = (uint*)(w + 1837056);       // 4 B
    float* out  = (float*)d_out;

    void* args[12] = {(void*)&x, (void*)&y, (void*)&z, (void*)&zb,
                      (void*)&rowM, (void*)&rowS, (void*)&colM, (void*)&colS,
                      (void*)&diag, (void*)&m123, (void*)&counter, (void*)&out};
    hipError_t err = hipLaunchCooperativeKernel((const void*)fused_all,
                                                dim3(512), dim3(512),
                                                args, 0u, stream);
    if (err != hipSuccess) {
        // Fallback: proven 3-kernel path
        (void)hipGetLastError();
        zconv_kernel<<<64, 256, 0, stream>>>(z, zb);
        gemm_fused<<<512, 512, 0, stream>>>(x, y, zb, z, rowM, rowS, colM, colS, diag, counter);
        combine_final<<<256, 256, 0, stream>>>(rowM, rowS, colM, colS, diag, m123, counter, out);
    }
}

// Round 2
// 148.762 us; speedup vs baseline: 1.5266x; 1.5266x over previous
//
#include <hip/hip_runtime.h>

#define DIM 512
#define BK 32
#define ASTRIDE 40   // ushorts per A-row: 32 payload + 8 pad (80B) -> conflict-free frag reads
#define NCOMB 32     // last NCOMB finisher blocks perform the combine tail
#define RTHRESH (512 - NCOMB)

typedef unsigned int uint;
typedef unsigned short ushort;
typedef __attribute__((ext_vector_type(8))) short short8;
typedef __attribute__((ext_vector_type(4))) float f32x4;

#define GLOAD_LDS(g, l) __builtin_amdgcn_global_load_lds( \
    (const __attribute__((address_space(1))) void*)(g), \
    (__attribute__((address_space(3))) void*)(l), 16, 0, 0)

// Pack two fp32 -> two bf16 (round-to-nearest-ish via +0x8000, then byte-perm pack).
__device__ __forceinline__ uint pack_bf16(float a, float b) {
    union { float f; uint u; } ua, ub;
    ua.f = a; ub.f = b;
    uint x0 = ua.u + 0x8000u;
    uint x1 = ub.u + 0x8000u;
    return __builtin_amdgcn_perm(x1, x0, 0x07060302);
}

// ---- convert z (256x512 fp32) to bf16 once; also zero the counters ----
__global__ void zconv_kernel(const float* __restrict__ z, ushort* __restrict__ zb,
                             uint* __restrict__ cnt) {
    if (blockIdx.x == 0 && threadIdx.x == 0) { cnt[0] = 0u; cnt[1] = 0u; }
    int t = blockIdx.x * 256 + threadIdx.x;
    int f = t * 8;
    float4 a = *(const float4*)(z + f);
    float4 b = *(const float4*)(z + f + 4);
    uint4 o;
    o.x = pack_bf16(a.x, a.y);
    o.y = pack_bf16(a.z, a.w);
    o.z = pack_bf16(b.x, b.y);
    o.w = pack_bf16(b.z, b.w);
    *(uint4*)(zb + f) = o;
}

// 512-thread-block reductions: only tid<256 carry data, all threads barrier.
__device__ __forceinline__ float blk_max512(float v, float* sm) {
    #pragma unroll
    for (int d = 1; d < 64; d <<= 1) v = fmaxf(v, __shfl_xor(v, d, 64));
    __syncthreads();
    if (threadIdx.x < 256 && (threadIdx.x & 63) == 0) sm[threadIdx.x >> 6] = v;
    __syncthreads();
    return fmaxf(fmaxf(sm[0], sm[1]), fmaxf(sm[2], sm[3]));
}
__device__ __forceinline__ float blk_sum512(float v, float* sm) {
    #pragma unroll
    for (int d = 1; d < 64; d <<= 1) v += __shfl_xor(v, d, 64);
    __syncthreads();
    if (threadIdx.x < 256 && (threadIdx.x & 63) == 0) sm[threadIdx.x >> 6] = v;
    __syncthreads();
    return sm[0] + sm[1] + sm[2] + sm[3];
}

// =====================================================================
// K2: fused diag + batched GEMM + LSE partials + rank-gated combine tail.
// block = (a, rt): computes T[a, rt*128:(rt+1)*128, 0:256]
// After partials are written, each block takes a finish-rank via atomic.
// The last NCOMB finishers wait for all 512 (deadlock-free: by the time
// any block spins, >=RTHRESH blocks have fully exited), then perform the
// per-index LSE combine (8 indices per block) and the final reduction.
// Combine reduction trees are bitwise-identical to the proven separate
// combine kernel (active lanes are exactly waves 0..3).
// =====================================================================
__global__ void __launch_bounds__(512, 4)
gemm_fused(const float* __restrict__ x, const float* __restrict__ y,
           const ushort* __restrict__ zb, const float* __restrict__ z,
           float* __restrict__ rowM, float* __restrict__ rowS,
           float* __restrict__ colM, float* __restrict__ colS,
           float* __restrict__ diag, float* __restrict__ m123,
           uint* __restrict__ cnt, float* __restrict__ out) {
    __shared__ __align__(16) float xs[DIM];
    __shared__ __align__(16) ushort As[2][128 * ASTRIDE];
    __shared__ __align__(16) ushort Bs[2][256 * BK];
    __shared__ float redA[128 * 4];
    __shared__ float rowMaxS[128];
    __shared__ float redB[256 * 2];
    __shared__ float colMaxS[256];
    __shared__ float dred[8];
    __shared__ uint rankS;
    __shared__ uint lastS;

    const int tid = threadIdx.x;
    const int a   = blockIdx.x >> 1;
    const int rt  = blockIdx.x & 1;

    xs[tid] = x[a * DIM + tid];

    const int lane = tid & 63;
    const int wave = tid >> 6;
    const int quad = lane >> 4;
    const int ln15 = lane & 15;
    const int wr = wave >> 2;
    const int wc = wave & 3;

    // ---- fused diag: T[a,a,a] exact fp32 (rt==0 blocks only) ----
    if (rt == 0) {
        float p = xs[tid] * y[a * DIM + tid] * z[a * DIM + tid];
        #pragma unroll
        for (int m = 1; m < 64; m <<= 1) p += __shfl_xor(p, m, 64);
        if (lane == 0) dred[wave] = p;
        __syncthreads();
        if (tid == 0) {
            float s = 0.f;
            #pragma unroll
            for (int w2 = 0; w2 < 8; ++w2) s += dred[w2];
            diag[a] = s;
        }
    }
    __syncthreads();   // xs visible to all (also covers rt==1 blocks)

    f32x4 acc[4][4];
    #pragma unroll
    for (int i = 0; i < 4; ++i)
        #pragma unroll
        for (int j = 0; j < 4; ++j)
            acc[i][j] = (f32x4){0.f, 0.f, 0.f, 0.f};

    // A staging coords: 8 bf16 per thread
    const int rA = tid >> 2;            // 0..127
    const int kA = (tid & 3) * 8;       // 0,8,16,24
    const float* yrow = y + (rt * 128 + rA) * DIM + kA;

    // B DMA coords: 2 slots/thread; slot s -> row = s>>2, kc = ((s&3)-(row>>1))&3
    const int s0 = wave * 128 + lane;
    const int row0 = s0 >> 2, kc0 = ((s0 & 3) - (row0 >> 1)) & 3;
    const ushort* gB0 = zb + row0 * DIM + kc0 * 8;
    const int s1 = s0 + 64;
    const int row1 = s1 >> 2, kc1 = ((s1 & 3) - (row1 >> 1)) & 3;
    const ushort* gB1 = zb + row1 * DIM + kc1 * 8;

    // ---- prologue: stage tile 0, prefetch y[1] ----
    GLOAD_LDS(gB0, &Bs[0][wave * 1024]);
    GLOAD_LDS(gB1, &Bs[0][wave * 1024 + 512]);
    float4 ya = *(const float4*)(yrow);
    float4 yb = *(const float4*)(yrow + 4);
    {
        float4 x0 = *(const float4*)(xs + kA);
        float4 x1 = *(const float4*)(xs + kA + 4);
        uint4 o;
        o.x = pack_bf16(ya.x * x0.x, ya.y * x0.y);
        o.y = pack_bf16(ya.z * x0.z, ya.w * x0.w);
        o.z = pack_bf16(yb.x * x1.x, yb.y * x1.y);
        o.w = pack_bf16(yb.z * x1.z, yb.w * x1.w);
        *(uint4*)(&As[0][rA * ASTRIDE + kA]) = o;
    }
    ya = *(const float4*)(yrow + 32);
    yb = *(const float4*)(yrow + 36);

    #pragma unroll 2
    for (int kt = 0; kt < 16; ++kt) {
        const int cur = kt & 1, nxt = cur ^ 1;
        __syncthreads();   // As[cur]/Bs[cur] ready; drains in-flight prefetches
        if (kt < 15) {     // launch B DMA for kt+1 into the other buffer
            GLOAD_LDS(gB0 + (kt + 1) * 32, &Bs[nxt][wave * 1024]);
            GLOAD_LDS(gB1 + (kt + 1) * 32, &Bs[nxt][wave * 1024 + 512]);
        }
        short8 af[4], bfr[4];
        #pragma unroll
        for (int i = 0; i < 4; ++i)
            af[i] = *(const short8*)(&As[cur][(wr * 64 + i * 16 + ln15) * ASTRIDE + quad * 8]);
        #pragma unroll
        for (int j = 0; j < 4; ++j) {
            int row = wc * 64 + j * 16 + ln15;
            int pos = row * 4 + ((quad + (row >> 1)) & 3);
            bfr[j] = *(const short8*)(&Bs[cur][pos * 8]);
        }
        #pragma unroll
        for (int i = 0; i < 4; ++i)
            #pragma unroll
            for (int j = 0; j < 4; ++j)
                acc[i][j] = __builtin_amdgcn_mfma_f32_16x16x32_bf16(af[i], bfr[j], acc[i][j], 0, 0, 0);
        if (kt < 15) {     // pack A for kt+1 from prefetched y regs
            const int k1 = (kt + 1) * 32;
            float4 x0 = *(const float4*)(xs + k1 + kA);
            float4 x1 = *(const float4*)(xs + k1 + kA + 4);
            uint4 o;
            o.x = pack_bf16(ya.x * x0.x, ya.y * x0.y);
            o.y = pack_bf16(ya.z * x0.z, ya.w * x0.w);
            o.z = pack_bf16(yb.x * x1.x, yb.y * x1.y);
            o.w = pack_bf16(yb.z * x1.z, yb.w * x1.w);
            *(uint4*)(&As[nxt][rA * ASTRIDE + kA]) = o;
            if (kt < 14) {  // prefetch y for kt+2
                ya = *(const float4*)(yrow + (kt + 2) * 32);
                yb = *(const float4*)(yrow + (kt + 2) * 32 + 4);
            }
        }
    }
    __syncthreads();

    // ===== row-wise LSE partials (reduce over all 256 cols s) =====
    #pragma unroll
    for (int i = 0; i < 4; ++i) {
        #pragma unroll
        for (int reg = 0; reg < 4; ++reg) {
            float m = fmaxf(fmaxf(acc[i][0][reg], acc[i][1][reg]),
                            fmaxf(acc[i][2][reg], acc[i][3][reg]));
            #pragma unroll
            for (int d = 1; d < 16; d <<= 1) m = fmaxf(m, __shfl_xor(m, d, 64));
            if (ln15 == 0) redA[(wr * 64 + i * 16 + quad * 4 + reg) * 4 + wc] = m;
        }
    }
    __syncthreads();
    if (tid < 128) {
        float m = fmaxf(fmaxf(redA[tid * 4 + 0], redA[tid * 4 + 1]),
                        fmaxf(redA[tid * 4 + 2], redA[tid * 4 + 3]));
        rowMaxS[tid] = m;
    }
    __syncthreads();
    #pragma unroll
    for (int i = 0; i < 4; ++i) {
        #pragma unroll
        for (int reg = 0; reg < 4; ++reg) {
            int r = wr * 64 + i * 16 + quad * 4 + reg;
            float rm = rowMaxS[r];
            float s = __expf(acc[i][0][reg] - rm) + __expf(acc[i][1][reg] - rm)
                    + __expf(acc[i][2][reg] - rm) + __expf(acc[i][3][reg] - rm);
            #pragma unroll
            for (int d = 1; d < 16; d <<= 1) s += __shfl_xor(s, d, 64);
            if (ln15 == 0) redA[r * 4 + wc] = s;
        }
    }
    __syncthreads();
    if (tid < 128) {
        float s = redA[tid * 4 + 0] + redA[tid * 4 + 1] + redA[tid * 4 + 2] + redA[tid * 4 + 3];
        int rg = rt * 128 + tid;
        rowM[a * 256 + rg] = rowMaxS[tid];
        rowS[a * 256 + rg] = s;
    }

    // ===== col-wise LSE partials (reduce over this block's 128 rows) =====
    #pragma unroll
    for (int j = 0; j < 4; ++j) {
        float m = -3.4e38f;
        #pragma unroll
        for (int i = 0; i < 4; ++i)
            #pragma unroll
            for (int reg = 0; reg < 4; ++reg)
                m = fmaxf(m, acc[i][j][reg]);
        m = fmaxf(m, __shfl_xor(m, 16, 64));
        m = fmaxf(m, __shfl_xor(m, 32, 64));
        if (quad == 0) redB[(wc * 64 + j * 16 + ln15) * 2 + wr] = m;
    }
    __syncthreads();
    if (tid < 256) colMaxS[tid] = fmaxf(redB[tid * 2], redB[tid * 2 + 1]);
    __syncthreads();
    #pragma unroll
    for (int j = 0; j < 4; ++j) {
        int n = wc * 64 + j * 16 + ln15;
        float cm = colMaxS[n];
        float s = 0.f;
        #pragma unroll
        for (int i = 0; i < 4; ++i)
            #pragma unroll
            for (int reg = 0; reg < 4; ++reg)
                s += __expf(acc[i][j][reg] - cm);
        s += __shfl_xor(s, 16, 64);
        s += __shfl_xor(s, 32, 64);
        if (quad == 0) redB[n * 2 + wr] = s;
    }
    __syncthreads();
    if (tid < 256) {
        float s = redB[tid * 2] + redB[tid * 2 + 1];
        colM[(a * 256 + tid) * 2 + rt] = colMaxS[tid];
        colS[(a * 256 + tid) * 2 + rt] = s;
    }

    // ===== rank gate: take a finish rank; early finishers exit =====
    __syncthreads();          // all partial stores issued (vmcnt drained per wave)
    if (tid == 0) {
        __threadfence();      // release: partials visible device-wide
        rankS = atomicAdd(&cnt[0], 1u);
    }
    __syncthreads();
    const uint rank = rankS;
    if (rank < (uint)RTHRESH) return;

    // last NCOMB finishers: wait for all 512 blocks, then combine
    if (tid == 0) {
        while (__hip_atomic_load(&cnt[0], __ATOMIC_RELAXED, __HIP_MEMORY_SCOPE_AGENT) < 512u) {
            __builtin_amdgcn_s_sleep(1);
        }
    }
    __syncthreads();
    __threadfence();          // acquire: see all blocks' partials

    const volatile float* vRowM = (const volatile float*)rowM;
    const volatile float* vRowS = (const volatile float*)rowS;
    const volatile float* vColM = (const volatile float*)colM;
    const volatile float* vColS = (const volatile float*)colS;

    const int bBase = (int)(rank - (uint)RTHRESH) * (256 / NCOMB);
    #pragma unroll 1
    for (int k = 0; k < 256 / NCOMB; ++k) {
        const int b = bBase + k;
        const int t = tid;
        const bool act = t < 256;
        float m = act ? vRowM[b * 256 + t] : -3.4e38f;
        float s = act ? vRowS[b * 256 + t] : 0.f;
        float M = blk_max512(m, dred);
        float S = blk_sum512(act ? s * __expf(m - M) : 0.f, dred);
        float M1 = M + __logf(S);
        m = act ? vRowM[t * 256 + b] : -3.4e38f;
        s = act ? vRowS[t * 256 + b] : 0.f;
        M = blk_max512(m, dred);
        S = blk_sum512(act ? s * __expf(m - M) : 0.f, dred);
        float M2 = M + __logf(S);
        float am = act ? vColM[(t * 256 + b) * 2 + 0] : -3.4e38f;
        float av = act ? vColS[(t * 256 + b) * 2 + 0] : 0.f;
        float bm = act ? vColM[(t * 256 + b) * 2 + 1] : -3.4e38f;
        float bv = act ? vColS[(t * 256 + b) * 2 + 1] : 0.f;
        m = fmaxf(am, bm);
        s = av * __expf(am - m) + bv * __expf(bm - m);
        M = blk_max512(m, dred);
        S = blk_sum512(act ? s * __expf(m - M) : 0.f, dred);
        float M3 = M + __logf(S);
        if (t == 0) m123[b] = M1 + M2 + M3;
        __syncthreads();
    }

    // ===== final reduction by the last combiner =====
    if (tid == 0) {
        __threadfence();
        lastS = (atomicAdd(&cnt[1], 1u) == (uint)(NCOMB - 1)) ? 1u : 0u;
    }
    __syncthreads();
    if (lastS) {
        __threadfence();
        const volatile float* vm = (const volatile float*)m123;
        const volatile float* vd = (const volatile float*)diag;
        float S1 = blk_sum512(tid < 256 ? vm[tid] : 0.f, dred);
        float S2 = blk_sum512(tid < 256 ? vd[tid] : 0.f, dred);
        if (tid == 0) out[0] = S1 / 768.0f - S2 / 256.0f;
    }
}

extern "C" void kernel_launch(void* const* d_in, const int* in_sizes, int n_in,
                              void* d_out, int out_size, void* d_ws, size_t ws_size,
                              hipStream_t stream) {
    const float* x = (const float*)d_in[0];
    const float* y = (const float*)d_in[1];
    const float* z = (const float*)d_in[2];
    char* w = (char*)d_ws;
    ushort* zb  = (ushort*)(w);                  // 262144 B
    float* rowM = (float*)(w + 262144);          // 262144 B
    float* rowS = (float*)(w + 524288);          // 262144 B
    float* colM = (float*)(w + 786432);          // 524288 B
    float* colS = (float*)(w + 1310720);         // 524288 B
    float* diag = (float*)(w + 1835008);         // 1024 B
    float* m123 = (float*)(w + 1836032);         // 1024 B
    uint*  cnt  = (uint*)(w + 1837056);          // 8 B
    float* out  = (float*)d_out;

    zconv_kernel<<<64, 256, 0, stream>>>(z, zb, cnt);
    gemm_fused<<<512, 512, 0, stream>>>(x, y, zb, z, rowM, rowS, colM, colS,
                                        diag, m123, cnt, out);
}

// Round 3
// 98.836 us; speedup vs baseline: 2.2977x; 1.5051x over previous
//
#include <hip/hip_runtime.h>

#define DIM 512
#define BK 32
#define ASTRIDE 40   // ushorts per A-row: 32 payload + 8 pad (80B) -> conflict-free frag reads

typedef unsigned int uint;
typedef unsigned short ushort;
typedef __attribute__((ext_vector_type(8))) short short8;
typedef __attribute__((ext_vector_type(4))) float f32x4;

// Pack two fp32 -> two bf16 (round-to-nearest-ish via +0x8000, then byte-perm pack).
__device__ __forceinline__ uint pack_bf16(float a, float b) {
    union { float f; uint u; } ua, ub;
    ua.f = a; ub.f = b;
    uint x0 = ua.u + 0x8000u;
    uint x1 = ub.u + 0x8000u;
    return __builtin_amdgcn_perm(x1, x0, 0x07060302);
}

// =====================================================================
// K1: fused diag + batched GEMM + LSE partials.
// block = (a, rt): computes T[a, rt*128:(rt+1)*128, 0:256]
// B-staging now converts fp32 z in-loop (reg-stage -> pack -> ds_write),
// eliminating the former zconv kernel and its launch gap. Rounding is
// identical to the old zconv (same pack_bf16), so results are bitwise
// identical. One barrier per ktile; y and z register prefetches are one
// iteration ahead, packed+written at the end of each iteration.
// B slot swizzle: pos(row,kc) = row*4 + ((kc + (row>>1)) & 3)  (16B slots)
// =====================================================================
__global__ void __launch_bounds__(512, 4)
gemm_fused(const float* __restrict__ x, const float* __restrict__ y,
           const float* __restrict__ z,
           float* __restrict__ rowM, float* __restrict__ rowS,
           float* __restrict__ colM, float* __restrict__ colS,
           float* __restrict__ diag, uint* __restrict__ counter) {
    __shared__ __align__(16) float xs[DIM];
    __shared__ __align__(16) ushort As[2][128 * ASTRIDE];
    __shared__ __align__(16) ushort Bs[2][256 * BK];
    __shared__ float redA[128 * 4];
    __shared__ float rowMaxS[128];
    __shared__ float redB[256 * 2];
    __shared__ float colMaxS[256];
    __shared__ float dred[8];

    const int tid = threadIdx.x;
    const int a   = blockIdx.x >> 1;
    const int rt  = blockIdx.x & 1;

    if (blockIdx.x == 0 && tid == 0) *counter = 0u;   // reset K2's flag each call

    xs[tid] = x[a * DIM + tid];

    const int lane = tid & 63;
    const int wave = tid >> 6;
    const int quad = lane >> 4;
    const int ln15 = lane & 15;
    const int wr = wave >> 2;
    const int wc = wave & 3;

    // A staging coords: 8 bf16 per thread
    const int rA = tid >> 2;            // 0..127
    const int kA = (tid & 3) * 8;       // 0,8,16,24
    const float* yrow = y + (rt * 128 + rA) * DIM + kA;

    // B staging coords: 2 slots/thread; slot s -> row = s>>2, kc = ((s&3)-(row>>1))&3
    const int s0 = wave * 128 + lane;
    const int row0 = s0 >> 2, kc0 = ((s0 & 3) - (row0 >> 1)) & 3;
    const float* gz0 = z + row0 * DIM + kc0 * 8;
    const int s1 = s0 + 64;
    const int row1 = s1 >> 2, kc1 = ((s1 & 3) - (row1 >> 1)) & 3;
    const float* gz1 = z + row1 * DIM + kc1 * 8;

    // ---- issue tile-0 global loads early (latency hides under diag) ----
    float4 ya  = *(const float4*)(yrow);
    float4 yb  = *(const float4*)(yrow + 4);
    float4 z0a = *(const float4*)(gz0);
    float4 z0b = *(const float4*)(gz0 + 4);
    float4 z1a = *(const float4*)(gz1);
    float4 z1b = *(const float4*)(gz1 + 4);

    // ---- fused diag: T[a,a,a] exact fp32 (rt==0 blocks only) ----
    if (rt == 0) {
        float p = xs[tid] * y[a * DIM + tid] * z[a * DIM + tid];
        #pragma unroll
        for (int m = 1; m < 64; m <<= 1) p += __shfl_xor(p, m, 64);
        if (lane == 0) dred[wave] = p;
        __syncthreads();
        if (tid == 0) {
            float s = 0.f;
            #pragma unroll
            for (int w2 = 0; w2 < 8; ++w2) s += dred[w2];
            diag[a] = s;
        }
    }
    __syncthreads();   // xs visible to all (also covers rt==1 blocks)

    f32x4 acc[4][4];
    #pragma unroll
    for (int i = 0; i < 4; ++i)
        #pragma unroll
        for (int j = 0; j < 4; ++j)
            acc[i][j] = (f32x4){0.f, 0.f, 0.f, 0.f};

    // ---- prologue: pack tile 0 into buf0, prefetch tile-1 regs ----
    {
        float4 x0 = *(const float4*)(xs + kA);
        float4 x1 = *(const float4*)(xs + kA + 4);
        uint4 o;
        o.x = pack_bf16(ya.x * x0.x, ya.y * x0.y);
        o.y = pack_bf16(ya.z * x0.z, ya.w * x0.w);
        o.z = pack_bf16(yb.x * x1.x, yb.y * x1.y);
        o.w = pack_bf16(yb.z * x1.z, yb.w * x1.w);
        *(uint4*)(&As[0][rA * ASTRIDE + kA]) = o;
        uint4 ob;
        ob.x = pack_bf16(z0a.x, z0a.y);
        ob.y = pack_bf16(z0a.z, z0a.w);
        ob.z = pack_bf16(z0b.x, z0b.y);
        ob.w = pack_bf16(z0b.z, z0b.w);
        *(uint4*)(&Bs[0][s0 * 8]) = ob;
        ob.x = pack_bf16(z1a.x, z1a.y);
        ob.y = pack_bf16(z1a.z, z1a.w);
        ob.z = pack_bf16(z1b.x, z1b.y);
        ob.w = pack_bf16(z1b.z, z1b.w);
        *(uint4*)(&Bs[0][s1 * 8]) = ob;
    }
    ya  = *(const float4*)(yrow + 32);
    yb  = *(const float4*)(yrow + 36);
    z0a = *(const float4*)(gz0 + 32);
    z0b = *(const float4*)(gz0 + 36);
    z1a = *(const float4*)(gz1 + 32);
    z1b = *(const float4*)(gz1 + 36);

    #pragma unroll 2
    for (int kt = 0; kt < 16; ++kt) {
        const int cur = kt & 1, nxt = cur ^ 1;
        __syncthreads();   // As[cur]/Bs[cur] (written last iter) ready
        short8 bfr[4];
        #pragma unroll
        for (int j = 0; j < 4; ++j) {
            int row = wc * 64 + j * 16 + ln15;
            int pos = row * 4 + ((quad + (row >> 1)) & 3);
            bfr[j] = *(const short8*)(&Bs[cur][pos * 8]);
        }
        __builtin_amdgcn_s_setprio(1);
        #pragma unroll
        for (int i = 0; i < 4; ++i) {
            short8 af = *(const short8*)(&As[cur][(wr * 64 + i * 16 + ln15) * ASTRIDE + quad * 8]);
            #pragma unroll
            for (int j = 0; j < 4; ++j)
                acc[i][j] = __builtin_amdgcn_mfma_f32_16x16x32_bf16(af, bfr[j], acc[i][j], 0, 0, 0);
        }
        __builtin_amdgcn_s_setprio(0);
        if (kt < 15) {     // pack tile kt+1 from prefetched regs
            const int k1 = (kt + 1) * 32;
            float4 x0 = *(const float4*)(xs + k1 + kA);
            float4 x1 = *(const float4*)(xs + k1 + kA + 4);
            uint4 o;
            o.x = pack_bf16(ya.x * x0.x, ya.y * x0.y);
            o.y = pack_bf16(ya.z * x0.z, ya.w * x0.w);
            o.z = pack_bf16(yb.x * x1.x, yb.y * x1.y);
            o.w = pack_bf16(yb.z * x1.z, yb.w * x1.w);
            *(uint4*)(&As[nxt][rA * ASTRIDE + kA]) = o;
            uint4 ob;
            ob.x = pack_bf16(z0a.x, z0a.y);
            ob.y = pack_bf16(z0a.z, z0a.w);
            ob.z = pack_bf16(z0b.x, z0b.y);
            ob.w = pack_bf16(z0b.z, z0b.w);
            *(uint4*)(&Bs[nxt][s0 * 8]) = ob;
            ob.x = pack_bf16(z1a.x, z1a.y);
            ob.y = pack_bf16(z1a.z, z1a.w);
            ob.z = pack_bf16(z1b.x, z1b.y);
            ob.w = pack_bf16(z1b.z, z1b.w);
            *(uint4*)(&Bs[nxt][s1 * 8]) = ob;
            if (kt < 14) {  // prefetch regs for kt+2
                ya  = *(const float4*)(yrow + (kt + 2) * 32);
                yb  = *(const float4*)(yrow + (kt + 2) * 32 + 4);
                z0a = *(const float4*)(gz0 + (kt + 2) * 32);
                z0b = *(const float4*)(gz0 + (kt + 2) * 32 + 4);
                z1a = *(const float4*)(gz1 + (kt + 2) * 32);
                z1b = *(const float4*)(gz1 + (kt + 2) * 32 + 4);
            }
        }
    }
    __syncthreads();

    // ===== row-wise LSE partials (reduce over all 256 cols s) =====
    #pragma unroll
    for (int i = 0; i < 4; ++i) {
        #pragma unroll
        for (int reg = 0; reg < 4; ++reg) {
            float m = fmaxf(fmaxf(acc[i][0][reg], acc[i][1][reg]),
                            fmaxf(acc[i][2][reg], acc[i][3][reg]));
            #pragma unroll
            for (int d = 1; d < 16; d <<= 1) m = fmaxf(m, __shfl_xor(m, d, 64));
            if (ln15 == 0) redA[(wr * 64 + i * 16 + quad * 4 + reg) * 4 + wc] = m;
        }
    }
    __syncthreads();
    if (tid < 128) {
        float m = fmaxf(fmaxf(redA[tid * 4 + 0], redA[tid * 4 + 1]),
                        fmaxf(redA[tid * 4 + 2], redA[tid * 4 + 3]));
        rowMaxS[tid] = m;
    }
    __syncthreads();
    #pragma unroll
    for (int i = 0; i < 4; ++i) {
        #pragma unroll
        for (int reg = 0; reg < 4; ++reg) {
            int r = wr * 64 + i * 16 + quad * 4 + reg;
            float rm = rowMaxS[r];
            float s = __expf(acc[i][0][reg] - rm) + __expf(acc[i][1][reg] - rm)
                    + __expf(acc[i][2][reg] - rm) + __expf(acc[i][3][reg] - rm);
            #pragma unroll
            for (int d = 1; d < 16; d <<= 1) s += __shfl_xor(s, d, 64);
            if (ln15 == 0) redA[r * 4 + wc] = s;
        }
    }
    __syncthreads();
    if (tid < 128) {
        float s = redA[tid * 4 + 0] + redA[tid * 4 + 1] + redA[tid * 4 + 2] + redA[tid * 4 + 3];
        int rg = rt * 128 + tid;
        rowM[a * 256 + rg] = rowMaxS[tid];
        rowS[a * 256 + rg] = s;
    }

    // ===== col-wise LSE partials (reduce over this block's 128 rows) =====
    #pragma unroll
    for (int j = 0; j < 4; ++j) {
        float m = -3.4e38f;
        #pragma unroll
        for (int i = 0; i < 4; ++i)
            #pragma unroll
            for (int reg = 0; reg < 4; ++reg)
                m = fmaxf(m, acc[i][j][reg]);
        m = fmaxf(m, __shfl_xor(m, 16, 64));
        m = fmaxf(m, __shfl_xor(m, 32, 64));
        if (quad == 0) redB[(wc * 64 + j * 16 + ln15) * 2 + wr] = m;
    }
    __syncthreads();
    if (tid < 256) colMaxS[tid] = fmaxf(redB[tid * 2], redB[tid * 2 + 1]);
    __syncthreads();
    #pragma unroll
    for (int j = 0; j < 4; ++j) {
        int n = wc * 64 + j * 16 + ln15;
        float cm = colMaxS[n];
        float s = 0.f;
        #pragma unroll
        for (int i = 0; i < 4; ++i)
            #pragma unroll
            for (int reg = 0; reg < 4; ++reg)
                s += __expf(acc[i][j][reg] - cm);
        s += __shfl_xor(s, 16, 64);
        s += __shfl_xor(s, 32, 64);
        if (quad == 0) redB[n * 2 + wr] = s;
    }
    __syncthreads();
    if (tid < 256) {
        float s = redB[tid * 2] + redB[tid * 2 + 1];
        colM[(a * 256 + tid) * 2 + rt] = colMaxS[tid];
        colS[(a * 256 + tid) * 2 + rt] = s;
    }
}

// ---- block-wide reductions over 256 threads ----
__device__ __forceinline__ float blk_max(float v, float* sm) {
    #pragma unroll
    for (int d = 1; d < 64; d <<= 1) v = fmaxf(v, __shfl_xor(v, d, 64));
    __syncthreads();
    if ((threadIdx.x & 63) == 0) sm[threadIdx.x >> 6] = v;
    __syncthreads();
    return fmaxf(fmaxf(sm[0], sm[1]), fmaxf(sm[2], sm[3]));
}
__device__ __forceinline__ float blk_sum(float v, float* sm) {
    #pragma unroll
    for (int d = 1; d < 64; d <<= 1) v += __shfl_xor(v, d, 64);
    __syncthreads();
    if ((threadIdx.x & 63) == 0) sm[threadIdx.x >> 6] = v;
    __syncthreads();
    return sm[0] + sm[1] + sm[2] + sm[3];
}

// =====================================================================
// K2: per-index LSE combine + last-block final reduction
// =====================================================================
__global__ void combine_final(const float* __restrict__ rowM, const float* __restrict__ rowS,
                              const float* __restrict__ colM, const float* __restrict__ colS,
                              const float* __restrict__ diag,
                              float* __restrict__ m123, uint* __restrict__ counter,
                              float* __restrict__ out) {
    __shared__ float sm[4];
    __shared__ uint isLast;
    int b = blockIdx.x, t = threadIdx.x;
    float m = rowM[b * 256 + t], s = rowS[b * 256 + t];
    float M = blk_max(m, sm);
    float S = blk_sum(s * __expf(m - M), sm);
    float M1 = M + __logf(S);
    m = rowM[t * 256 + b]; s = rowS[t * 256 + b];
    M = blk_max(m, sm);
    S = blk_sum(s * __expf(m - M), sm);
    float M2 = M + __logf(S);
    float am = colM[(t * 256 + b) * 2 + 0], av = colS[(t * 256 + b) * 2 + 0];
    float bm = colM[(t * 256 + b) * 2 + 1], bv = colS[(t * 256 + b) * 2 + 1];
    m = fmaxf(am, bm);
    s = av * __expf(am - m) + bv * __expf(bm - m);
    M = blk_max(m, sm);
    S = blk_sum(s * __expf(m - M), sm);
    float M3 = M + __logf(S);
    if (t == 0) {
        m123[b] = M1 + M2 + M3;
        __threadfence();
        isLast = (atomicAdd(counter, 1u) == 255u) ? 1u : 0u;
    }
    __syncthreads();
    if (isLast) {
        __threadfence();
        const volatile float* vm = (const volatile float*)m123;
        const volatile float* vd = (const volatile float*)diag;
        float S1 = blk_sum(vm[t], sm);
        float S2 = blk_sum(vd[t], sm);
        if (t == 0) out[0] = S1 / 768.0f - S2 / 256.0f;
    }
}

extern "C" void kernel_launch(void* const* d_in, const int* in_sizes, int n_in,
                              void* d_out, int out_size, void* d_ws, size_t ws_size,
                              hipStream_t stream) {
    const float* x = (const float*)d_in[0];
    const float* y = (const float*)d_in[1];
    const float* z = (const float*)d_in[2];
    char* w = (char*)d_ws;
    float* rowM = (float*)(w + 262144);          // 262144 B
    float* rowS = (float*)(w + 524288);          // 262144 B
    float* colM = (float*)(w + 786432);          // 524288 B
    float* colS = (float*)(w + 1310720);         // 524288 B
    float* diag = (float*)(w + 1835008);         // 1024 B
    float* m123 = (float*)(w + 1836032);         // 1024 B
    uint*  counter = (uint*)(w + 1837056);       // 4 B
    float* out  = (float*)d_out;

    gemm_fused<<<512, 512, 0, stream>>>(x, y, z, rowM, rowS, colM, colS, diag, counter);
    combine_final<<<256, 256, 0, stream>>>(rowM, rowS, colM, colS, diag, m123, counter, out);
}